// Round 1
// baseline (369.822 us; speedup 1.0000x reference)
//
#include <hip/hip_runtime.h>

typedef __attribute__((ext_vector_type(8))) short short8;
typedef __attribute__((ext_vector_type(4))) short short4v;
typedef __attribute__((ext_vector_type(4))) float f32x4;

__device__ __forceinline__ short f2bf(float f) {
  union { float f; unsigned u; } v; v.f = f;
  unsigned r = v.u + 0x7fffu + ((v.u >> 16) & 1u);
  return (short)(r >> 16);
}

__device__ __forceinline__ f32x4 fzero4() {
  f32x4 z; z[0] = 0.f; z[1] = 0.f; z[2] = 0.f; z[3] = 0.f; return z;
}

// ---------- fp32 -> bf16 conversion of x1, x2, Wq, Wk, Wv, Wo ----------
// segments (elements): x1 4194304 | x2 8388608 | Wq/Wk/Wv/Wo 1048576 each
__global__ __launch_bounds__(256) void cvt_all(
    const float* __restrict__ x1, const float* __restrict__ x2,
    const float* __restrict__ wq, const float* __restrict__ wk,
    const float* __restrict__ wv, const float* __restrict__ wo,
    short* __restrict__ dst) {
  long e = ((long)blockIdx.x * 256 + threadIdx.x) * 4;
  const float* src; long loc;
  if (e < 4194304L)       { src = x1; loc = e; }
  else if (e < 12582912L) { src = x2; loc = e - 4194304L; }
  else if (e < 13631488L) { src = wq; loc = e - 12582912L; }
  else if (e < 14680064L) { src = wk; loc = e - 13631488L; }
  else if (e < 15728640L) { src = wv; loc = e - 14680064L; }
  else                    { src = wo; loc = e - 15728640L; }
  float4 v = *(const float4*)(src + loc);
  short4v o;
  o[0] = f2bf(v.x); o[1] = f2bf(v.y); o[2] = f2bf(v.z); o[3] = f2bf(v.w);
  *(short4v*)(dst + e) = o;
}

// ---------- bf16 NT GEMM: C[M,1024] = A[M,1024] @ W[1024,1024]^T + bias ----------
// EPI 0: write bf16 permuted [B,H,S,D] (S = 1<<lgS); EPI 1: write fp32 plain [M,1024]
// grid: (8, M/128), block 256 (4 waves in 2x2, each 64x64 via 4x4 mfma 16x16x32)
template<int EPI>
__global__ __launch_bounds__(256) void gemm_nt(
    const short* __restrict__ A, const short* __restrict__ W,
    const float* __restrict__ bias, void* __restrict__ out, int lgS) {
  __shared__ short As[128][40];
  __shared__ short Bs[128][40];
  const int tid = threadIdx.x;
  const int w = tid >> 6, lane = tid & 63;
  const int quad = lane >> 4, col = lane & 15;
  const int waveM = (w >> 1) * 64, waveN = (w & 1) * 64;
  const int bn = blockIdx.x * 128, bm = blockIdx.y * 128;
  const int srow = tid >> 1, sc0 = (tid & 1) * 16;

  f32x4 acc[4][4];
  for (int mi = 0; mi < 4; ++mi)
    for (int ni = 0; ni < 4; ++ni)
      acc[mi][ni] = fzero4();

  const short* ap = A + (size_t)(bm + srow) * 1024 + sc0;
  const short* bp = W + (size_t)(bn + srow) * 1024 + sc0;

  for (int kk = 0; kk < 1024; kk += 32) {
    short8 a0 = *(const short8*)(ap + kk);
    short8 a1 = *(const short8*)(ap + kk + 8);
    short8 b0 = *(const short8*)(bp + kk);
    short8 b1 = *(const short8*)(bp + kk + 8);
    __syncthreads();  // previous iteration's LDS reads complete
    *(short8*)&As[srow][sc0]     = a0;
    *(short8*)&As[srow][sc0 + 8] = a1;
    *(short8*)&Bs[srow][sc0]     = b0;
    *(short8*)&Bs[srow][sc0 + 8] = b1;
    __syncthreads();
    short8 af[4], bf[4];
    for (int mi = 0; mi < 4; ++mi)
      af[mi] = *(const short8*)&As[waveM + mi * 16 + col][quad * 8];
    for (int ni = 0; ni < 4; ++ni)
      bf[ni] = *(const short8*)&Bs[waveN + ni * 16 + col][quad * 8];
    for (int mi = 0; mi < 4; ++mi)
      for (int ni = 0; ni < 4; ++ni)
        acc[mi][ni] = __builtin_amdgcn_mfma_f32_16x16x32_bf16(af[mi], bf[ni], acc[mi][ni], 0, 0, 0);
  }

  for (int ni = 0; ni < 4; ++ni) {
    int n = bn + waveN + ni * 16 + col;
    float bv = bias[n];
    for (int mi = 0; mi < 4; ++mi) {
      int m0 = bm + waveM + mi * 16 + quad * 4;
      for (int r = 0; r < 4; ++r) {
        float val = acc[mi][ni][r] + bv;
        int m = m0 + r;
        if (EPI == 0) {
          int S = 1 << lgS;
          int bb = m >> lgS, s = m & (S - 1);
          int hh = n >> 6, d = n & 63;
          ((short*)out)[(((size_t)(bb * 16 + hh)) * S + s) * 64 + d] = f2bf(val);
        } else {
          ((float*)out)[(size_t)m * 1024 + n] = val;
        }
      }
    }
  }
}

// ---------- flash attention: q [BH,1024,64], k/v [BH,2048,64] bf16 -> O [4096,1024] bf16 ----------
// grid 1024: blockIdx.x = bh*16 + qtile; block 256 (4 waves, each 16 q-rows)
__global__ __launch_bounds__(256) void attn(
    const short* __restrict__ Q, const short* __restrict__ K,
    const short* __restrict__ V, short* __restrict__ O) {
  __shared__ short Qs[64][72];
  __shared__ short Ks[64][72];
  __shared__ short Vs[64][72];  // transposed: Vs[d][kv]
  __shared__ short Ps[64][72];
  const int tid = threadIdx.x;
  const int w = tid >> 6, lane = tid & 63;
  const int quad = lane >> 4, col = lane & 15;
  const int bh = blockIdx.x >> 4, qt = blockIdx.x & 15;
  const int b = bh >> 4, h = bh & 15;
  const int qbase = w * 16;

  const short* qp = Q + ((size_t)bh * 1024 + qt * 64) * 64;
  const short* kp = K + (size_t)bh * 2048 * 64;
  const short* vp = V + (size_t)bh * 2048 * 64;

  {  // stage Q tile (64x64)
    int r = tid >> 2, c0 = (tid & 3) * 16;
    short8 q0 = *(const short8*)(qp + r * 64 + c0);
    short8 q1 = *(const short8*)(qp + r * 64 + c0 + 8);
    *(short8*)&Qs[r][c0]     = q0;
    *(short8*)&Qs[r][c0 + 8] = q1;
  }

  float m_run[4], l_run[4];
  f32x4 o_acc[4];
  for (int r = 0; r < 4; ++r) { m_run[r] = -1e30f; l_run[r] = 0.f; }
  for (int ni = 0; ni < 4; ++ni) o_acc[ni] = fzero4();

  const int sr = tid >> 2, sc0 = (tid & 3) * 16;  // K staging
  const int vs = tid & 63, vd0 = (tid >> 6) * 8;  // V staging (transpose)

  for (int kt = 0; kt < 32; ++kt) {
    const short* kpp = kp + (size_t)(kt * 64 + sr) * 64 + sc0;
    short8 k0 = *(const short8*)kpp;
    short8 k1 = *(const short8*)(kpp + 8);
    const short* vpp = vp + (size_t)(kt * 64 + vs) * 64;
    short8 v0 = *(const short8*)(vpp + vd0);
    short8 v1 = *(const short8*)(vpp + vd0 + 32);
    __syncthreads();  // prior tile's K/V/P reads complete (covers Q staging on kt=0 too)
    *(short8*)&Ks[sr][sc0]     = k0;
    *(short8*)&Ks[sr][sc0 + 8] = k1;
    for (int j = 0; j < 8; ++j) Vs[vd0 + j][vs]      = v0[j];
    for (int j = 0; j < 8; ++j) Vs[vd0 + 32 + j][vs] = v1[j];
    __syncthreads();

    // S = Q K^T (each wave: its 16 q-rows x 64 kv)
    short8 aq0 = *(const short8*)&Qs[qbase + col][quad * 8];
    short8 aq1 = *(const short8*)&Qs[qbase + col][32 + quad * 8];
    f32x4 sf[4];
    for (int nk = 0; nk < 4; ++nk) {
      short8 bk0 = *(const short8*)&Ks[nk * 16 + col][quad * 8];
      short8 bk1 = *(const short8*)&Ks[nk * 16 + col][32 + quad * 8];
      f32x4 z = fzero4();
      z = __builtin_amdgcn_mfma_f32_16x16x32_bf16(aq0, bk0, z, 0, 0, 0);
      z = __builtin_amdgcn_mfma_f32_16x16x32_bf16(aq1, bk1, z, 0, 0, 0);
      sf[nk] = z;
    }

    // online softmax; lane holds rows quad*4+r, cols nk*16+col
    const float sc = 0.125f;  // 1/sqrt(64)
    float tm[4], mn[4], al[4];
    for (int r = 0; r < 4; ++r) {
      float a = fmaxf(fmaxf(sf[0][r], sf[1][r]), fmaxf(sf[2][r], sf[3][r])) * sc;
      for (int off = 1; off < 16; off <<= 1)
        a = fmaxf(a, __shfl_xor(a, off));
      tm[r] = a;
      mn[r] = fmaxf(m_run[r], tm[r]);
      al[r] = __expf(m_run[r] - mn[r]);
      m_run[r] = mn[r];
    }
    f32x4 pf[4];
    for (int nk = 0; nk < 4; ++nk)
      for (int r = 0; r < 4; ++r)
        pf[nk][r] = __expf(sf[nk][r] * sc - mn[r]);
    for (int r = 0; r < 4; ++r) {
      float rs = pf[0][r] + pf[1][r] + pf[2][r] + pf[3][r];
      for (int off = 1; off < 16; off <<= 1)
        rs += __shfl_xor(rs, off);
      l_run[r] = l_run[r] * al[r] + rs;
    }
    for (int ni = 0; ni < 4; ++ni)
      for (int r = 0; r < 4; ++r)
        o_acc[ni][r] *= al[r];

    // P -> LDS (C/D layout -> row-major [q][kv])
    for (int nk = 0; nk < 4; ++nk)
      for (int r = 0; r < 4; ++r)
        Ps[qbase + quad * 4 + r][nk * 16 + col] = f2bf(pf[nk][r]);
    __syncthreads();

    // O += P V
    short8 ap0 = *(const short8*)&Ps[qbase + col][quad * 8];
    short8 ap1 = *(const short8*)&Ps[qbase + col][32 + quad * 8];
    for (int ni = 0; ni < 4; ++ni) {
      short8 bv0 = *(const short8*)&Vs[ni * 16 + col][quad * 8];
      short8 bv1 = *(const short8*)&Vs[ni * 16 + col][32 + quad * 8];
      o_acc[ni] = __builtin_amdgcn_mfma_f32_16x16x32_bf16(ap0, bv0, o_acc[ni], 0, 0, 0);
      o_acc[ni] = __builtin_amdgcn_mfma_f32_16x16x32_bf16(ap1, bv1, o_acc[ni], 0, 0, 0);
    }
  }

  float inv[4];
  for (int r = 0; r < 4; ++r) inv[r] = 1.f / l_run[r];
  const size_t orow = (size_t)(b * 1024 + qt * 64 + qbase + quad * 4);
  for (int ni = 0; ni < 4; ++ni) {
    int cg = h * 64 + ni * 16 + col;
    for (int r = 0; r < 4; ++r)
      O[(orow + r) * 1024 + cg] = f2bf(o_acc[ni][r] * inv[r]);
  }
}

// ---------- launcher ----------
extern "C" void kernel_launch(void* const* d_in, const int* in_sizes, int n_in,
                              void* d_out, int out_size, void* d_ws, size_t ws_size,
                              hipStream_t stream) {
  const float* x1 = (const float*)d_in[0];
  const float* x2 = (const float*)d_in[1];
  const float* Wq = (const float*)d_in[2];
  const float* bq = (const float*)d_in[3];
  const float* Wk = (const float*)d_in[4];
  const float* bk = (const float*)d_in[5];
  const float* Wv = (const float*)d_in[6];
  const float* bv = (const float*)d_in[7];
  const float* Wo = (const float*)d_in[8];
  const float* bo = (const float*)d_in[9];

  char* ws = (char*)d_ws;
  // workspace layout (bytes):
  short* xb1 = (short*)(ws + 0);         // x1 bf16, 8 MB
  short* xb2 = (short*)(ws + 8388608);   // x2 bf16, 16 MB
  short* wqb = (short*)(ws + 25165824);  // Wq bf16, 2 MB
  short* wkb = (short*)(ws + 27262976);
  short* wvb = (short*)(ws + 29360128);
  short* wob = (short*)(ws + 31457280);
  short* qb  = (short*)(ws + 33554432);  // q [B,H,1024,64] bf16, 8 MB
  short* kb  = (short*)(ws + 41943040);  // k [B,H,2048,64] bf16, 16 MB
  short* vb  = (short*)(ws + 58720256);  // v [B,H,2048,64] bf16, 16 MB
  short* ob  = (short*)(ws + 75497472);  // attn out [4096,1024] bf16, 8 MB

  cvt_all<<<16384, 256, 0, stream>>>(x1, x2, Wq, Wk, Wv, Wo, (short*)ws);
  gemm_nt<0><<<dim3(8, 32), 256, 0, stream>>>(xb1, wqb, bq, qb, 10);
  gemm_nt<0><<<dim3(8, 64), 256, 0, stream>>>(xb2, wkb, bk, kb, 11);
  gemm_nt<0><<<dim3(8, 64), 256, 0, stream>>>(xb2, wvb, bv, vb, 11);
  attn<<<1024, 256, 0, stream>>>(qb, kb, vb, ob);
  gemm_nt<1><<<dim3(8, 32), 256, 0, stream>>>(ob, wob, bo, d_out, 0);
}